// Round 1
// baseline (346.090 us; speedup 1.0000x reference)
//
#include <hip/hip_runtime.h>
#include <hip/hip_bf16.h>

// GNN: 2-layer GraphConv (DGL norm='both'), N=100000, E=1600000.
// Round 15: kill k_place's scattered-write amplification (72.5MB written for
// a 6.4MB payload; dur tracked WRITE_SIZE at ~860GB/s across r12/r13).
// k_place now counting-sorts each 4096-edge chunk into its OWN contiguous
// 16KB ebuf region (block-local LDS hist + scan + place) and emits an
// offs[block][bucket] segment table. Writes become XCD-L2-local full lines
// -> WRITE_SIZE ~9MB. Global bcur reserve atomics deleted. k_sort2 gathers
// its bucket's edges from the 391 per-block segments (L3-resident reads,
// reads don't pay the partial-line penalty writes do); its hist/scan/scatter
// body and ALL downstream layouts (csrc/ostart/oend/nI/dO) are unchanged.
// Agg kernels keep r13's uint2 gathers (4 edges/VMEM agg64, 8 edges/VMEM agg32).

#define BSH 7                 // 128 nodes per bucket
#define BNODES 128
#define SRCMASK 0x1FFFF       // src < 131072
#define CAP 2560              // csrc bucket capacity (mean 2048, sigma~45)
#define CHUNK 4096            // edges per place-block (391 blocks)

__device__ __forceinline__ unsigned short f2bf(float f) {
    unsigned int u = __float_as_uint(f);
    return (unsigned short)((u + 0x7FFFu + ((u >> 16) & 1u)) >> 16);  // RNE
}

// ---------------- place: block-local counting sort of each chunk ------------
// Phase 1: LDS bucket histogram + fused out-degree atomics.
// Scan over 800 buckets (Hillis-Steele), write per-block segment offsets
// (801 ints: exclusive bases + total sentinel), then place edges into the
// block's OWN contiguous region [e0, e1) grouped by bucket. All ebuf stores
// hit the local XCD L2 and write back as full lines exactly once.
__global__ __launch_bounds__(1024) void k_place(const int* __restrict__ src,
        const int* __restrict__ dst, int* __restrict__ ebuf,
        int* __restrict__ offs, int* __restrict__ dO, int E, int NB) {
    __shared__ int lh[800], s[800];
    int t = threadIdx.x;
    int e0 = blockIdx.x * CHUNK;
    int e1 = min(e0 + CHUNK, E);
    if (t < 800) lh[t] = 0;
    __syncthreads();
    for (int i = e0 + t; i < e1; i += 1024) {
        atomicAdd(&lh[dst[i] >> BSH], 1);
        atomicAdd(&dO[src[i]], 1);
    }
    __syncthreads();
    if (t < 800) s[t] = lh[t];
    __syncthreads();
    for (int o = 1; o < 800; o <<= 1) {            // inclusive scan, 10 rounds
        int u = (t < 800 && t >= o) ? s[t - o] : 0;
        __syncthreads();
        if (t < 800) s[t] += u;
        __syncthreads();
    }
    int obase = blockIdx.x * 801;
    if (t < 800) {
        int base = s[t] - lh[t];                   // exclusive base
        offs[obase + t] = base;
        s[t] = base;                               // reuse s as base
        lh[t] = 0;                                 // reuse lh as cursor
    }
    if (t == 0) offs[obase + 800] = e1 - e0;       // total sentinel (no race)
    __syncthreads();
    for (int i = e0 + t; i < e1; i += 1024) {
        int sv = src[i], d = dst[i], b = d >> BSH; // src/dst L2-hot from ph.1
        int pos = e0 + s[b] + atomicAdd(&lh[b], 1);
        ebuf[pos] = sv | ((d & (BNODES - 1)) << 17);
    }
}

// ---------------- sort2: per-block segments -> per-node CSR + nI ------------
// Block = bucket. Gathers the bucket's edges from NBLK short segments
// (segst/segen from offs table), 8-lane groups per segment. Two passes over
// L3/L2-resident data: hist then scatter — same body as before, new addressing.
__global__ __launch_bounds__(1024) void k_sort2(const int* __restrict__ ebuf,
        const int* __restrict__ offs, int* __restrict__ csrc,
        int* __restrict__ ostart, int* __restrict__ oend,
        float* __restrict__ nI, int n, int NBLK) {
    __shared__ int cnt[BNODES], cur[BNODES], s[BNODES];
    __shared__ int segst[400], segen[400];
    int t = threadIdx.x, b = blockIdx.x;
    if (t < NBLK) {
        segst[t] = t * CHUNK + offs[t * 801 + b];
        segen[t] = t * CHUNK + offs[t * 801 + b + 1];
    }
    if (t < BNODES) cnt[t] = 0;
    __syncthreads();
    int grp = t >> 3, ln = t & 7;                  // 128 groups x 8 lanes
    for (int sg = grp; sg < NBLK; sg += 128) {
        int en = segen[sg];
        for (int i = segst[sg] + ln; i < en; i += 8)
            atomicAdd(&cnt[ebuf[i] >> 17], 1);
    }
    __syncthreads();
    if (t < BNODES) s[t] = cnt[t];
    __syncthreads();
    for (int o = 1; o < BNODES; o <<= 1) {
        int u = (t < BNODES && t >= o) ? s[t - o] : 0;
        __syncthreads();
        if (t < BNODES) s[t] += u;
        __syncthreads();
    }
    if (t < BNODES) {
        int e0 = b * CAP;
        int st = e0 + s[t] - cnt[t];
        cur[t] = st;
        int g = b * BNODES + t;
        if (g < n) {
            ostart[g] = st;
            oend[g] = e0 + s[t];
            nI[g] = rsqrtf(fmaxf((float)cnt[t], 1.0f));
        }
    }
    __syncthreads();
    for (int sg = grp; sg < NBLK; sg += 128) {
        int en = segen[sg];
        for (int i = segst[sg] + ln; i < en; i += 8) {
            int p = ebuf[i];                       // L2-hot from pass 1
            int pos = atomicAdd(&cur[p >> 17], 1);
            csrc[pos] = p & SRCMASK;
        }
    }
}

// ---------------- GEMM1: h1(bf16) = (x*rsqrt(dO)) @ W1, 128->64 -------------
__global__ __launch_bounds__(256) void k_gemm1(const float* __restrict__ x,
                        const float* __restrict__ W1, const int* __restrict__ dO,
                        unsigned short* __restrict__ h1, int n) {
    __shared__ float sX[64 * 132];
    __shared__ float sW[128 * 64];
    const int t = threadIdx.x;
    {
        const float4* W4 = (const float4*)W1;
        float4* sW4 = (float4*)sW;
#pragma unroll
        for (int i = 0; i < 8; i++) sW4[t + 256 * i] = W4[t + 256 * i];
    }
    const int rowbase = blockIdx.x * 64;
    {
        const float4* x4 = (const float4*)x;
        float4* sX4 = (float4*)sX;
#pragma unroll
        for (int i = 0; i < 8; i++) {
            int f = t + 256 * i;
            int row = f >> 5, kc = f & 31;
            int grow = rowbase + row;
            float4 v = make_float4(0.f, 0.f, 0.f, 0.f);
            if (grow < n) v = x4[(size_t)grow * 32 + kc];
            sX4[row * 33 + kc] = v;
        }
    }
    __syncthreads();
    const int lane = t & 63, wv = t >> 6;
    const int rg = lane >> 2, cg = lane & 3;
    const int c0 = wv * 16 + cg * 4;
    float acc[4][4] = {};
    for (int kk = 0; kk < 128; kk += 4) {
        float xr[4][4], wr[4][4];
#pragma unroll
        for (int i = 0; i < 4; i++)
            *(float4*)xr[i] = *(const float4*)&sX[(rg + 16 * i) * 132 + kk];
#pragma unroll
        for (int j = 0; j < 4; j++)
            *(float4*)wr[j] = *(const float4*)&sW[(kk + j) * 64 + c0];
#pragma unroll
        for (int j = 0; j < 4; j++)
#pragma unroll
            for (int i = 0; i < 4; i++)
#pragma unroll
                for (int c = 0; c < 4; c++)
                    acc[i][c] = fmaf(xr[i][j], wr[j][c], acc[i][c]);
    }
#pragma unroll
    for (int i = 0; i < 4; i++) {
        int grow = rowbase + rg + 16 * i;
        if (grow < n) {
            float nf = rsqrtf(fmaxf((float)dO[grow], 1.0f));
            ushort4 o;
            o.x = f2bf(acc[i][0] * nf); o.y = f2bf(acc[i][1] * nf);
            o.z = f2bf(acc[i][2] * nf); o.w = f2bf(acc[i][3] * nf);
            *(ushort4*)&h1[(size_t)grow * 64 + c0] = o;
        }
    }
}

// ---------------- agg1: wave/node, uint2 loads = 4 edges/VMEM ---------------
__global__ void k_agg64(const unsigned short* __restrict__ h,
                        const int* __restrict__ csrc,
                        const int* __restrict__ ostart, const int* __restrict__ oend,
                        const float* __restrict__ nI, const float* __restrict__ b1,
                        float* __restrict__ x2, int n) {
    int node = blockIdx.x * 4 + (threadIdx.x >> 6);
    int lane = threadIdx.x & 63;
    if (node >= n) return;
    int s0 = ostart[node], s1 = oend[node];
    int sub = lane >> 4;
    int c4 = (lane & 15) * 4;
    float a0 = 0.f, a1 = 0.f, a2 = 0.f, a3 = 0.f;
    float d0 = 0.f, d1 = 0.f, d2 = 0.f, d3 = 0.f;
    int e = s0;
    for (; e + 7 < s1; e += 8) {                 // 8 edges, 2 uint2 loads/lane
        int p0 = csrc[e + sub];
        int p1 = csrc[e + 4 + sub];
        uint2 u0 = *(const uint2*)&h[(size_t)p0 * 64 + c4];
        uint2 u1 = *(const uint2*)&h[(size_t)p1 * 64 + c4];
        a0 += __uint_as_float(u0.x << 16);
        a1 += __uint_as_float(u0.x & 0xFFFF0000u);
        a2 += __uint_as_float(u0.y << 16);
        a3 += __uint_as_float(u0.y & 0xFFFF0000u);
        d0 += __uint_as_float(u1.x << 16);
        d1 += __uint_as_float(u1.x & 0xFFFF0000u);
        d2 += __uint_as_float(u1.y << 16);
        d3 += __uint_as_float(u1.y & 0xFFFF0000u);
    }
    for (; e < s1; e += 4) {                     // tail, guarded
        if (e + sub < s1) {
            int p = csrc[e + sub];
            uint2 u = *(const uint2*)&h[(size_t)p * 64 + c4];
            a0 += __uint_as_float(u.x << 16);
            a1 += __uint_as_float(u.x & 0xFFFF0000u);
            a2 += __uint_as_float(u.y << 16);
            a3 += __uint_as_float(u.y & 0xFFFF0000u);
        }
    }
    a0 += d0; a1 += d1; a2 += d2; a3 += d3;
    a0 += __shfl(a0, lane ^ 16, 64);
    a1 += __shfl(a1, lane ^ 16, 64);
    a2 += __shfl(a2, lane ^ 16, 64);
    a3 += __shfl(a3, lane ^ 16, 64);
    a0 += __shfl(a0, lane ^ 32, 64);
    a1 += __shfl(a1, lane ^ 32, 64);
    a2 += __shfl(a2, lane ^ 32, 64);
    a3 += __shfl(a3, lane ^ 32, 64);
    if (sub == 0) {
        float ni = nI[node];
        float4 o;
        o.x = fmaxf(fmaf(a0, ni, b1[c4 + 0]), 0.f);
        o.y = fmaxf(fmaf(a1, ni, b1[c4 + 1]), 0.f);
        o.z = fmaxf(fmaf(a2, ni, b1[c4 + 2]), 0.f);
        o.w = fmaxf(fmaf(a3, ni, b1[c4 + 3]), 0.f);
        *(float4*)&x2[(size_t)node * 64 + c4] = o;
    }
}

// ---------------- GEMM2: h2(bf16) = (x2*rsqrt(dO)) @ W2, 64->32 -------------
__global__ __launch_bounds__(256) void k_gemm2(const float* __restrict__ x2,
                        const float* __restrict__ W2, const int* __restrict__ dO,
                        unsigned short* __restrict__ h2, int n) {
    __shared__ float sX[128 * 68];
    __shared__ float sW[64 * 32];
    const int t = threadIdx.x;
    {
        const float4* W4 = (const float4*)W2;
        float4* sW4 = (float4*)sW;
#pragma unroll
        for (int i = 0; i < 2; i++) sW4[t + 256 * i] = W4[t + 256 * i];
    }
    const int rowbase = blockIdx.x * 128;
    {
        const float4* x4 = (const float4*)x2;
        float4* sX4 = (float4*)sX;
#pragma unroll
        for (int i = 0; i < 8; i++) {
            int f = t + 256 * i;
            int row = f >> 4, kc = f & 15;
            int grow = rowbase + row;
            float4 v = make_float4(0.f, 0.f, 0.f, 0.f);
            if (grow < n) v = x4[(size_t)grow * 16 + kc];
            sX4[row * 17 + kc] = v;
        }
    }
    __syncthreads();
    const int lane = t & 63, wv = t >> 6;
    const int whalf = wv >> 1, chalf = wv & 1;
    const int rg = lane >> 2, cg = lane & 3;
    const int c0 = chalf * 16 + cg * 4;
    const int rloc = whalf * 64 + rg;
    float acc[4][4] = {};
    for (int kk = 0; kk < 64; kk += 4) {
        float xr[4][4], wr[4][4];
#pragma unroll
        for (int i = 0; i < 4; i++)
            *(float4*)xr[i] = *(const float4*)&sX[(rloc + 16 * i) * 68 + kk];
#pragma unroll
        for (int j = 0; j < 4; j++)
            *(float4*)wr[j] = *(const float4*)&sW[(kk + j) * 32 + c0];
#pragma unroll
        for (int j = 0; j < 4; j++)
#pragma unroll
            for (int i = 0; i < 4; i++)
#pragma unroll
                for (int c = 0; c < 4; c++)
                    acc[i][c] = fmaf(xr[i][j], wr[j][c], acc[i][c]);
    }
#pragma unroll
    for (int i = 0; i < 4; i++) {
        int grow = rowbase + rloc + 16 * i;
        if (grow < n) {
            float nf = rsqrtf(fmaxf((float)dO[grow], 1.0f));
            ushort4 o;
            o.x = f2bf(acc[i][0] * nf); o.y = f2bf(acc[i][1] * nf);
            o.z = f2bf(acc[i][2] * nf); o.w = f2bf(acc[i][3] * nf);
            *(ushort4*)&h2[(size_t)grow * 32 + c0] = o;
        }
    }
}

// ---------------- agg2: wave/node, uint2 loads = 8 edges/VMEM ---------------
__global__ void k_agg32(const unsigned short* __restrict__ h,
                        const int* __restrict__ csrc,
                        const int* __restrict__ ostart, const int* __restrict__ oend,
                        const float* __restrict__ nI, const float* __restrict__ b2,
                        float* __restrict__ out, int n) {
    int node = blockIdx.x * 4 + (threadIdx.x >> 6);
    int lane = threadIdx.x & 63;
    if (node >= n) return;
    int s0 = ostart[node], s1 = oend[node];
    int sub = lane >> 3;
    int c4 = (lane & 7) * 4;
    float a0 = 0.f, a1 = 0.f, a2 = 0.f, a3 = 0.f;
    float d0 = 0.f, d1 = 0.f, d2 = 0.f, d3 = 0.f;
    int e = s0;
    for (; e + 15 < s1; e += 16) {               // 16 edges, 2 uint2 loads/lane
        int p0 = csrc[e + sub];
        int p1 = csrc[e + 8 + sub];
        uint2 u0 = *(const uint2*)&h[(size_t)p0 * 32 + c4];
        uint2 u1 = *(const uint2*)&h[(size_t)p1 * 32 + c4];
        a0 += __uint_as_float(u0.x << 16);
        a1 += __uint_as_float(u0.x & 0xFFFF0000u);
        a2 += __uint_as_float(u0.y << 16);
        a3 += __uint_as_float(u0.y & 0xFFFF0000u);
        d0 += __uint_as_float(u1.x << 16);
        d1 += __uint_as_float(u1.x & 0xFFFF0000u);
        d2 += __uint_as_float(u1.y << 16);
        d3 += __uint_as_float(u1.y & 0xFFFF0000u);
    }
    for (; e < s1; e += 8) {                     // tail, guarded
        if (e + sub < s1) {
            int p = csrc[e + sub];
            uint2 u = *(const uint2*)&h[(size_t)p * 32 + c4];
            a0 += __uint_as_float(u.x << 16);
            a1 += __uint_as_float(u.x & 0xFFFF0000u);
            a2 += __uint_as_float(u.y << 16);
            a3 += __uint_as_float(u.y & 0xFFFF0000u);
        }
    }
    a0 += d0; a1 += d1; a2 += d2; a3 += d3;
    a0 += __shfl(a0, lane ^ 8, 64);
    a1 += __shfl(a1, lane ^ 8, 64);
    a2 += __shfl(a2, lane ^ 8, 64);
    a3 += __shfl(a3, lane ^ 8, 64);
    a0 += __shfl(a0, lane ^ 16, 64);
    a1 += __shfl(a1, lane ^ 16, 64);
    a2 += __shfl(a2, lane ^ 16, 64);
    a3 += __shfl(a3, lane ^ 16, 64);
    a0 += __shfl(a0, lane ^ 32, 64);
    a1 += __shfl(a1, lane ^ 32, 64);
    a2 += __shfl(a2, lane ^ 32, 64);
    a3 += __shfl(a3, lane ^ 32, 64);
    if (sub == 0) {
        float ni = nI[node];
        float4 o;
        o.x = fmaf(a0, ni, b2[c4 + 0]);
        o.y = fmaf(a1, ni, b2[c4 + 1]);
        o.z = fmaf(a2, ni, b2[c4 + 2]);
        o.w = fmaf(a3, ni, b2[c4 + 3]);
        *(float4*)&out[(size_t)node * 32 + c4] = o;
    }
}

extern "C" void kernel_launch(void* const* d_in, const int* in_sizes, int n_in,
                              void* d_out, int out_size, void* d_ws, size_t ws_size,
                              hipStream_t stream) {
    const float* x   = (const float*)d_in[0];  // [N,128]
    const int*   src = (const int*)d_in[1];    // [E]
    const int*   dst = (const int*)d_in[2];    // [E]
    const float* W1  = (const float*)d_in[3];  // [128,64]
    const float* b1  = (const float*)d_in[4];  // [64]
    const float* W2  = (const float*)d_in[5];  // [64,32]
    const float* b2  = (const float*)d_in[6];  // [32]
    float* out = (float*)d_out;                // [N,32]

    const int N = in_sizes[0] / 128;           // 100000
    const int E = in_sizes[1];                 // 1600000
    const int NB = (N + BNODES - 1) / BNODES;  // 782 buckets
    const int NBLK = (E + CHUNK - 1) / CHUNK;  // 391 place blocks

    char* wsb = (char*)d_ws;
    int*   dO     = (int*)wsb;    wsb += (size_t)N * 4;            // memset
    float* nI     = (float*)wsb;  wsb += (size_t)N * 4;
    int*   ostart = (int*)wsb;    wsb += (size_t)N * 4;
    int*   oend   = (int*)wsb;    wsb += (size_t)N * 4;
    int*   csrc   = (int*)wsb;    wsb += (size_t)NB * CAP * 4;     // 8.0 MB
    int*   offs   = (int*)wsb;    wsb += (size_t)NBLK * 801 * 4;   // 1.25 MB
    unsigned short* h1 = (unsigned short*)wsb;
                                  wsb += (size_t)N * 64 * 2;       // 12.8 MB bf16
    float* x2     = (float*)wsb;  wsb += (size_t)N * 64 * 4;       // 25.6 MB
    unsigned short* h2 = h1;      // h1 dead after k_agg64
    int*   ebuf   = (int*)x2;     // E*4 = 6.4 MB; dead before agg64 writes x2

    hipMemsetAsync(dO, 0, (size_t)N * sizeof(int), stream);

    // CSR build (degO fused into place phase 1; block-local sort + offs table)
    k_place<<<NBLK, 1024, 0, stream>>>(src, dst, ebuf, offs, dO, E, NB);
    k_sort2<<<NB, 1024, 0, stream>>>(ebuf, offs, csrc, ostart, oend, nI, N, NBLK);

    // layer 1
    k_gemm1<<<(N + 63) / 64, 256, 0, stream>>>(x, W1, dO, h1, N);
    k_agg64<<<(N + 3) / 4, 256, 0, stream>>>(h1, csrc, ostart, oend, nI, b1, x2, N);

    // layer 2
    k_gemm2<<<(N + 127) / 128, 256, 0, stream>>>(x2, W2, dO, h2, N);
    k_agg32<<<(N + 3) / 4, 256, 0, stream>>>(h2, csrc, ostart, oend, nI, b2, out, N);
}

// Round 2
// 296.993 us; speedup vs baseline: 1.1653x; 1.1653x over previous
//
#include <hip/hip_runtime.h>
#include <hip/hip_bf16.h>

// GNN: 2-layer GraphConv (DGL norm='both'), N=100000, E=1600000.
// Round 16: kill the per-edge device atomics. r15 post-mortem: WRITE_SIZE
// residual 49.8MB == 1.6M x 32B = dO atomicAdds (device-scope -> executed at
// memory side, one EA transaction each; per-XCD L2s aren't coherent). Fix:
// out-degree via a second block-local binned stream (1 byte/edge, src&127
// bucketed by src>>7). k_place's histogram+scan handle both sides with
// 16-bit packed counts (<=4096 each, no carry). k_sort2 counts its bucket's
// bytes in LDS and writes nO=rsqrt(deg) directly -- ZERO global atomics in
// the whole pipeline. GEMMs load nO; dO + its memset deleted.
// Agg kernels keep r13's uint2 gathers (4 edges/VMEM agg64, 8 edges/VMEM agg32).

#define BSH 7                 // 128 nodes per bucket
#define BNODES 128
#define SRCMASK 0x1FFFF       // src < 131072
#define CAP 2560              // csrc bucket capacity (mean 2048, sigma~45)
#define CHUNK 4096            // edges per place-block (391 blocks)

__device__ __forceinline__ unsigned short f2bf(float f) {
    unsigned int u = __float_as_uint(f);
    return (unsigned short)((u + 0x7FFFu + ((u >> 16) & 1u)) >> 16);  // RNE
}

// ---------------- place: block-local dual counting sort ---------------------
// Packed LDS hist: high16 = dst-bucket count, low16 = src-bucket count.
// One Hillis-Steele scan serves both. Phase 2 places the dst-keyed record
// into ebuf and the src low-7-bits byte into sbuf, both in the block's OWN
// contiguous region (full-line L2-local writebacks). Cursors packed in s[].
__global__ __launch_bounds__(1024) void k_place(const int* __restrict__ src,
        const int* __restrict__ dst, int* __restrict__ ebuf,
        unsigned char* __restrict__ sbuf, int* __restrict__ offs,
        int* __restrict__ soffs, int E) {
    __shared__ int lh[800], s[800];
    int t = threadIdx.x;
    int e0 = blockIdx.x * CHUNK;
    int e1 = min(e0 + CHUNK, E);
    if (t < 800) lh[t] = 0;
    __syncthreads();
    for (int i = e0 + t; i < e1; i += 1024) {
        atomicAdd(&lh[dst[i] >> BSH], 0x10000);
        atomicAdd(&lh[src[i] >> BSH], 1);
    }
    __syncthreads();
    if (t < 800) s[t] = lh[t];
    __syncthreads();
    for (int o = 1; o < 800; o <<= 1) {            // packed inclusive scan
        int u = (t < 800 && t >= o) ? s[t - o] : 0;
        __syncthreads();
        if (t < 800) s[t] += u;
        __syncthreads();
    }
    int obase = blockIdx.x * 801;
    if (t < 800) {
        int incl = s[t], c = lh[t];
        int bd = (incl >> 16) - (c >> 16);         // exclusive dst base
        int bs = (incl & 0xFFFF) - (c & 0xFFFF);   // exclusive src base
        offs[obase + t] = bd;
        soffs[obase + t] = bs;
        s[t] = (bd << 16) | bs;                    // packed cursors
    }
    if (t == 0) { offs[obase + 800] = e1 - e0; soffs[obase + 800] = e1 - e0; }
    __syncthreads();
    for (int i = e0 + t; i < e1; i += 1024) {
        int sv = src[i], d = dst[i];               // L2-hot from phase 1
        int pd = atomicAdd(&s[d >> BSH], 0x10000) >> 16;
        ebuf[e0 + pd] = sv | ((d & (BNODES - 1)) << 17);
        int ps = atomicAdd(&s[sv >> BSH], 1) & 0xFFFF;
        sbuf[e0 + ps] = (unsigned char)(sv & (BNODES - 1));
    }
}

// ---------------- sort2: segments -> CSR + nI + nO (no global atomics) ------
// Block = bucket. Pass 1: dst-hist from ebuf segments AND src-count from sbuf
// byte segments (same 8-lane-group walk). Writes ostart/oend/nI/nO, then
// scatters csrc. All heavy data L2/L3-resident (just written by k_place).
__global__ __launch_bounds__(1024) void k_sort2(const int* __restrict__ ebuf,
        const unsigned char* __restrict__ sbuf, const int* __restrict__ offs,
        const int* __restrict__ soffs, int* __restrict__ csrc,
        int* __restrict__ ostart, int* __restrict__ oend,
        float* __restrict__ nI, float* __restrict__ nO, int n, int NBLK) {
    __shared__ int cnt[BNODES], cur[BNODES], s[BNODES], scnt[BNODES];
    __shared__ int segst[400], segen[400], sst[400], sen[400];
    int t = threadIdx.x, b = blockIdx.x;
    if (t < NBLK) {
        segst[t] = t * CHUNK + offs[t * 801 + b];
        segen[t] = t * CHUNK + offs[t * 801 + b + 1];
        sst[t]   = t * CHUNK + soffs[t * 801 + b];
        sen[t]   = t * CHUNK + soffs[t * 801 + b + 1];
    }
    if (t < BNODES) { cnt[t] = 0; scnt[t] = 0; }
    __syncthreads();
    int grp = t >> 3, ln = t & 7;                  // 128 groups x 8 lanes
    for (int sg = grp; sg < NBLK; sg += 128) {
        int en = segen[sg];
        for (int i = segst[sg] + ln; i < en; i += 8)
            atomicAdd(&cnt[ebuf[i] >> 17], 1);
        int en2 = sen[sg];
        for (int i = sst[sg] + ln; i < en2; i += 8)
            atomicAdd(&scnt[sbuf[i]], 1);
    }
    __syncthreads();
    if (t < BNODES) s[t] = cnt[t];
    __syncthreads();
    for (int o = 1; o < BNODES; o <<= 1) {
        int u = (t < BNODES && t >= o) ? s[t - o] : 0;
        __syncthreads();
        if (t < BNODES) s[t] += u;
        __syncthreads();
    }
    if (t < BNODES) {
        int e0 = b * CAP;
        int st = e0 + s[t] - cnt[t];
        cur[t] = st;
        int g = b * BNODES + t;
        if (g < n) {
            ostart[g] = st;
            oend[g] = e0 + s[t];
            nI[g] = rsqrtf(fmaxf((float)cnt[t], 1.0f));
            nO[g] = rsqrtf(fmaxf((float)scnt[t], 1.0f));
        }
    }
    __syncthreads();
    for (int sg = grp; sg < NBLK; sg += 128) {
        int en = segen[sg];
        for (int i = segst[sg] + ln; i < en; i += 8) {
            int p = ebuf[i];                       // L2-hot from pass 1
            int pos = atomicAdd(&cur[p >> 17], 1);
            csrc[pos] = p & SRCMASK;
        }
    }
}

// ---------------- GEMM1: h1(bf16) = (x*nO) @ W1, 128->64 --------------------
__global__ __launch_bounds__(256) void k_gemm1(const float* __restrict__ x,
                        const float* __restrict__ W1, const float* __restrict__ nO,
                        unsigned short* __restrict__ h1, int n) {
    __shared__ float sX[64 * 132];
    __shared__ float sW[128 * 64];
    const int t = threadIdx.x;
    {
        const float4* W4 = (const float4*)W1;
        float4* sW4 = (float4*)sW;
#pragma unroll
        for (int i = 0; i < 8; i++) sW4[t + 256 * i] = W4[t + 256 * i];
    }
    const int rowbase = blockIdx.x * 64;
    {
        const float4* x4 = (const float4*)x;
        float4* sX4 = (float4*)sX;
#pragma unroll
        for (int i = 0; i < 8; i++) {
            int f = t + 256 * i;
            int row = f >> 5, kc = f & 31;
            int grow = rowbase + row;
            float4 v = make_float4(0.f, 0.f, 0.f, 0.f);
            if (grow < n) v = x4[(size_t)grow * 32 + kc];
            sX4[row * 33 + kc] = v;
        }
    }
    __syncthreads();
    const int lane = t & 63, wv = t >> 6;
    const int rg = lane >> 2, cg = lane & 3;
    const int c0 = wv * 16 + cg * 4;
    float acc[4][4] = {};
    for (int kk = 0; kk < 128; kk += 4) {
        float xr[4][4], wr[4][4];
#pragma unroll
        for (int i = 0; i < 4; i++)
            *(float4*)xr[i] = *(const float4*)&sX[(rg + 16 * i) * 132 + kk];
#pragma unroll
        for (int j = 0; j < 4; j++)
            *(float4*)wr[j] = *(const float4*)&sW[(kk + j) * 64 + c0];
#pragma unroll
        for (int j = 0; j < 4; j++)
#pragma unroll
            for (int i = 0; i < 4; i++)
#pragma unroll
                for (int c = 0; c < 4; c++)
                    acc[i][c] = fmaf(xr[i][j], wr[j][c], acc[i][c]);
    }
#pragma unroll
    for (int i = 0; i < 4; i++) {
        int grow = rowbase + rg + 16 * i;
        if (grow < n) {
            float nf = nO[grow];
            ushort4 o;
            o.x = f2bf(acc[i][0] * nf); o.y = f2bf(acc[i][1] * nf);
            o.z = f2bf(acc[i][2] * nf); o.w = f2bf(acc[i][3] * nf);
            *(ushort4*)&h1[(size_t)grow * 64 + c0] = o;
        }
    }
}

// ---------------- agg1: wave/node, uint2 loads = 4 edges/VMEM ---------------
__global__ void k_agg64(const unsigned short* __restrict__ h,
                        const int* __restrict__ csrc,
                        const int* __restrict__ ostart, const int* __restrict__ oend,
                        const float* __restrict__ nI, const float* __restrict__ b1,
                        float* __restrict__ x2, int n) {
    int node = blockIdx.x * 4 + (threadIdx.x >> 6);
    int lane = threadIdx.x & 63;
    if (node >= n) return;
    int s0 = ostart[node], s1 = oend[node];
    int sub = lane >> 4;
    int c4 = (lane & 15) * 4;
    float a0 = 0.f, a1 = 0.f, a2 = 0.f, a3 = 0.f;
    float d0 = 0.f, d1 = 0.f, d2 = 0.f, d3 = 0.f;
    int e = s0;
    for (; e + 7 < s1; e += 8) {                 // 8 edges, 2 uint2 loads/lane
        int p0 = csrc[e + sub];
        int p1 = csrc[e + 4 + sub];
        uint2 u0 = *(const uint2*)&h[(size_t)p0 * 64 + c4];
        uint2 u1 = *(const uint2*)&h[(size_t)p1 * 64 + c4];
        a0 += __uint_as_float(u0.x << 16);
        a1 += __uint_as_float(u0.x & 0xFFFF0000u);
        a2 += __uint_as_float(u0.y << 16);
        a3 += __uint_as_float(u0.y & 0xFFFF0000u);
        d0 += __uint_as_float(u1.x << 16);
        d1 += __uint_as_float(u1.x & 0xFFFF0000u);
        d2 += __uint_as_float(u1.y << 16);
        d3 += __uint_as_float(u1.y & 0xFFFF0000u);
    }
    for (; e < s1; e += 4) {                     // tail, guarded
        if (e + sub < s1) {
            int p = csrc[e + sub];
            uint2 u = *(const uint2*)&h[(size_t)p * 64 + c4];
            a0 += __uint_as_float(u.x << 16);
            a1 += __uint_as_float(u.x & 0xFFFF0000u);
            a2 += __uint_as_float(u.y << 16);
            a3 += __uint_as_float(u.y & 0xFFFF0000u);
        }
    }
    a0 += d0; a1 += d1; a2 += d2; a3 += d3;
    a0 += __shfl(a0, lane ^ 16, 64);
    a1 += __shfl(a1, lane ^ 16, 64);
    a2 += __shfl(a2, lane ^ 16, 64);
    a3 += __shfl(a3, lane ^ 16, 64);
    a0 += __shfl(a0, lane ^ 32, 64);
    a1 += __shfl(a1, lane ^ 32, 64);
    a2 += __shfl(a2, lane ^ 32, 64);
    a3 += __shfl(a3, lane ^ 32, 64);
    if (sub == 0) {
        float ni = nI[node];
        float4 o;
        o.x = fmaxf(fmaf(a0, ni, b1[c4 + 0]), 0.f);
        o.y = fmaxf(fmaf(a1, ni, b1[c4 + 1]), 0.f);
        o.z = fmaxf(fmaf(a2, ni, b1[c4 + 2]), 0.f);
        o.w = fmaxf(fmaf(a3, ni, b1[c4 + 3]), 0.f);
        *(float4*)&x2[(size_t)node * 64 + c4] = o;
    }
}

// ---------------- GEMM2: h2(bf16) = (x2*nO) @ W2, 64->32 --------------------
__global__ __launch_bounds__(256) void k_gemm2(const float* __restrict__ x2,
                        const float* __restrict__ W2, const float* __restrict__ nO,
                        unsigned short* __restrict__ h2, int n) {
    __shared__ float sX[128 * 68];
    __shared__ float sW[64 * 32];
    const int t = threadIdx.x;
    {
        const float4* W4 = (const float4*)W2;
        float4* sW4 = (float4*)sW;
#pragma unroll
        for (int i = 0; i < 2; i++) sW4[t + 256 * i] = W4[t + 256 * i];
    }
    const int rowbase = blockIdx.x * 128;
    {
        const float4* x4 = (const float4*)x2;
        float4* sX4 = (float4*)sX;
#pragma unroll
        for (int i = 0; i < 8; i++) {
            int f = t + 256 * i;
            int row = f >> 4, kc = f & 15;
            int grow = rowbase + row;
            float4 v = make_float4(0.f, 0.f, 0.f, 0.f);
            if (grow < n) v = x4[(size_t)grow * 16 + kc];
            sX4[row * 17 + kc] = v;
        }
    }
    __syncthreads();
    const int lane = t & 63, wv = t >> 6;
    const int whalf = wv >> 1, chalf = wv & 1;
    const int rg = lane >> 2, cg = lane & 3;
    const int c0 = chalf * 16 + cg * 4;
    const int rloc = whalf * 64 + rg;
    float acc[4][4] = {};
    for (int kk = 0; kk < 64; kk += 4) {
        float xr[4][4], wr[4][4];
#pragma unroll
        for (int i = 0; i < 4; i++)
            *(float4*)xr[i] = *(const float4*)&sX[(rloc + 16 * i) * 68 + kk];
#pragma unroll
        for (int j = 0; j < 4; j++)
            *(float4*)wr[j] = *(const float4*)&sW[(kk + j) * 32 + c0];
#pragma unroll
        for (int j = 0; j < 4; j++)
#pragma unroll
            for (int i = 0; i < 4; i++)
#pragma unroll
                for (int c = 0; c < 4; c++)
                    acc[i][c] = fmaf(xr[i][j], wr[j][c], acc[i][c]);
    }
#pragma unroll
    for (int i = 0; i < 4; i++) {
        int grow = rowbase + rloc + 16 * i;
        if (grow < n) {
            float nf = nO[grow];
            ushort4 o;
            o.x = f2bf(acc[i][0] * nf); o.y = f2bf(acc[i][1] * nf);
            o.z = f2bf(acc[i][2] * nf); o.w = f2bf(acc[i][3] * nf);
            *(ushort4*)&h2[(size_t)grow * 32 + c0] = o;
        }
    }
}

// ---------------- agg2: wave/node, uint2 loads = 8 edges/VMEM ---------------
__global__ void k_agg32(const unsigned short* __restrict__ h,
                        const int* __restrict__ csrc,
                        const int* __restrict__ ostart, const int* __restrict__ oend,
                        const float* __restrict__ nI, const float* __restrict__ b2,
                        float* __restrict__ out, int n) {
    int node = blockIdx.x * 4 + (threadIdx.x >> 6);
    int lane = threadIdx.x & 63;
    if (node >= n) return;
    int s0 = ostart[node], s1 = oend[node];
    int sub = lane >> 3;
    int c4 = (lane & 7) * 4;
    float a0 = 0.f, a1 = 0.f, a2 = 0.f, a3 = 0.f;
    float d0 = 0.f, d1 = 0.f, d2 = 0.f, d3 = 0.f;
    int e = s0;
    for (; e + 15 < s1; e += 16) {               // 16 edges, 2 uint2 loads/lane
        int p0 = csrc[e + sub];
        int p1 = csrc[e + 8 + sub];
        uint2 u0 = *(const uint2*)&h[(size_t)p0 * 32 + c4];
        uint2 u1 = *(const uint2*)&h[(size_t)p1 * 32 + c4];
        a0 += __uint_as_float(u0.x << 16);
        a1 += __uint_as_float(u0.x & 0xFFFF0000u);
        a2 += __uint_as_float(u0.y << 16);
        a3 += __uint_as_float(u0.y & 0xFFFF0000u);
        d0 += __uint_as_float(u1.x << 16);
        d1 += __uint_as_float(u1.x & 0xFFFF0000u);
        d2 += __uint_as_float(u1.y << 16);
        d3 += __uint_as_float(u1.y & 0xFFFF0000u);
    }
    for (; e < s1; e += 8) {                     // tail, guarded
        if (e + sub < s1) {
            int p = csrc[e + sub];
            uint2 u = *(const uint2*)&h[(size_t)p * 32 + c4];
            a0 += __uint_as_float(u.x << 16);
            a1 += __uint_as_float(u.x & 0xFFFF0000u);
            a2 += __uint_as_float(u.y << 16);
            a3 += __uint_as_float(u.y & 0xFFFF0000u);
        }
    }
    a0 += d0; a1 += d1; a2 += d2; a3 += d3;
    a0 += __shfl(a0, lane ^ 8, 64);
    a1 += __shfl(a1, lane ^ 8, 64);
    a2 += __shfl(a2, lane ^ 8, 64);
    a3 += __shfl(a3, lane ^ 8, 64);
    a0 += __shfl(a0, lane ^ 16, 64);
    a1 += __shfl(a1, lane ^ 16, 64);
    a2 += __shfl(a2, lane ^ 16, 64);
    a3 += __shfl(a3, lane ^ 16, 64);
    a0 += __shfl(a0, lane ^ 32, 64);
    a1 += __shfl(a1, lane ^ 32, 64);
    a2 += __shfl(a2, lane ^ 32, 64);
    a3 += __shfl(a3, lane ^ 32, 64);
    if (sub == 0) {
        float ni = nI[node];
        float4 o;
        o.x = fmaf(a0, ni, b2[c4 + 0]);
        o.y = fmaf(a1, ni, b2[c4 + 1]);
        o.z = fmaf(a2, ni, b2[c4 + 2]);
        o.w = fmaf(a3, ni, b2[c4 + 3]);
        *(float4*)&out[(size_t)node * 32 + c4] = o;
    }
}

extern "C" void kernel_launch(void* const* d_in, const int* in_sizes, int n_in,
                              void* d_out, int out_size, void* d_ws, size_t ws_size,
                              hipStream_t stream) {
    const float* x   = (const float*)d_in[0];  // [N,128]
    const int*   src = (const int*)d_in[1];    // [E]
    const int*   dst = (const int*)d_in[2];    // [E]
    const float* W1  = (const float*)d_in[3];  // [128,64]
    const float* b1  = (const float*)d_in[4];  // [64]
    const float* W2  = (const float*)d_in[5];  // [64,32]
    const float* b2  = (const float*)d_in[6];  // [32]
    float* out = (float*)d_out;                // [N,32]

    const int N = in_sizes[0] / 128;           // 100000
    const int E = in_sizes[1];                 // 1600000
    const int NB = (N + BNODES - 1) / BNODES;  // 782 buckets
    const int NBLK = (E + CHUNK - 1) / CHUNK;  // 391 place blocks

    char* wsb = (char*)d_ws;
    float* nO     = (float*)wsb;  wsb += (size_t)N * 4;
    float* nI     = (float*)wsb;  wsb += (size_t)N * 4;
    int*   ostart = (int*)wsb;    wsb += (size_t)N * 4;
    int*   oend   = (int*)wsb;    wsb += (size_t)N * 4;
    int*   csrc   = (int*)wsb;    wsb += (size_t)NB * CAP * 4;     // 8.0 MB
    int*   offs   = (int*)wsb;    wsb += (size_t)NBLK * 801 * 4;   // 1.25 MB
    unsigned short* h1 = (unsigned short*)wsb;
                                  wsb += (size_t)N * 64 * 2;       // 12.8 MB bf16
    float* x2     = (float*)wsb;  wsb += (size_t)N * 64 * 4;       // 25.6 MB
    unsigned short* h2 = h1;      // h1 dead after k_agg64
    // scratch aliased into x2 (dead before agg64 writes x2):
    int*   ebuf   = (int*)x2;                                      // 6.4 MB
    unsigned char* sbuf = (unsigned char*)(ebuf) + (size_t)E * 4;  // 1.6 MB
    int*   soffs  = (int*)(sbuf + (size_t)E);                      // 1.25 MB

    // CSR build — no memset, no global atomics anywhere
    k_place<<<NBLK, 1024, 0, stream>>>(src, dst, ebuf, sbuf, offs, soffs, E);
    k_sort2<<<NB, 1024, 0, stream>>>(ebuf, sbuf, offs, soffs, csrc,
                                     ostart, oend, nI, nO, N, NBLK);

    // layer 1
    k_gemm1<<<(N + 63) / 64, 256, 0, stream>>>(x, W1, nO, h1, N);
    k_agg64<<<(N + 3) / 4, 256, 0, stream>>>(h1, csrc, ostart, oend, nI, b1, x2, N);

    // layer 2
    k_gemm2<<<(N + 127) / 128, 256, 0, stream>>>(x2, W2, nO, h2, N);
    k_agg32<<<(N + 3) / 4, 256, 0, stream>>>(h2, csrc, ostart, oend, nI, b2, out, N);
}